// Round 16
// baseline (179.225 us; speedup 1.0000x reference)
//
#include <hip/hip_runtime.h>

#define H 64
#define G 64
#define OUT 2
#define MAXBUK 128
#define BSHIFT 10
#define CAP 12288

typedef unsigned int uint32;
using short8 = __attribute__((ext_vector_type(8))) short;
using f32x4  = __attribute__((ext_vector_type(4))) float;

union ABFrag { uint32 u[4]; uint4 q; short8 v; };

__device__ inline float bf16lo(uint32 u) { return __uint_as_float(u << 16); }
__device__ inline float bf16hi(uint32 u) { return __uint_as_float(u & 0xffff0000u); }
__device__ inline uint32 packbf16(float a, float b) {
    uint32 ua = __float_as_uint(a);
    uint32 ub = __float_as_uint(b);
    ua = (ua + 0x7fffu + ((ua >> 16) & 1u)) >> 16;                 // RNE
    ub = (ub + 0x7fffu + ((ub >> 16) & 1u)) & 0xffff0000u;         // RNE
    return ua | ub;
}

// ---------------- fused setup: prepW(W1) + zero pooled/bcnt/done ----------------
__global__ __launch_bounds__(256) void k_setup(const float* __restrict__ W1,
                                               uint32* __restrict__ Wb,
                                               float* __restrict__ pooled,
                                               int* __restrict__ bcnt,
                                               int* __restrict__ done) {
    int blk = blockIdx.x;
    int t = threadIdx.x;
    if (blk == 0) {
        for (int i = t; i < 2048; i += 256) {
            int r = i & 3;
            int lane = (i >> 2) & 63;
            int slot = i >> 8;
            int ct = slot >> 1, ks = slot & 1;
            int col = ct * 16 + (lane & 15);
            int k0 = ks * 32 + (lane >> 4) * 8;
            float a = W1[(k0 + 2 * r) * 64 + col];
            float b = W1[(k0 + 2 * r + 1) * 64 + col];
            Wb[i] = packbf16(a, b);
        }
    } else {
        for (int i = t; i < G * H; i += 256) pooled[i] = 0.0f;
        if (t < MAXBUK) bcnt[t] = 0;
        if (t == 0) *done = 0;
    }
}

// ---------------- bucket histogram + fused last-block scan ----------------
__global__ __launch_bounds__(256) void k_bhist(const int* __restrict__ dst,
                                               int* __restrict__ bcnt,
                                               int* __restrict__ bbase,
                                               int* __restrict__ bcur,
                                               int* __restrict__ done,
                                               int e, int nbuk) {
    __shared__ int hh[MAXBUK];
    for (int i = threadIdx.x; i < MAXBUK; i += 256) hh[i] = 0;
    __syncthreads();
    int stride = gridDim.x * 256;
    for (int i = blockIdx.x * 256 + threadIdx.x; i < e; i += stride)
        atomicAdd(&hh[__builtin_nontemporal_load(&dst[i]) >> BSHIFT], 1);
    __syncthreads();
    for (int i = threadIdx.x; i < nbuk; i += 256)
        if (hh[i]) atomicAdd(&bcnt[i], hh[i]);
    if (threadIdx.x == 0) {
        __threadfence();
        int ticket = atomicAdd(done, 1);
        if (ticket == (int)gridDim.x - 1) {
            int run = 0;
            for (int i = 0; i < nbuk; ++i) {
                int c = atomicAdd(&bcnt[i], 0);
                bbase[i] = run; bcur[i] = run; run += c;
            }
            bbase[nbuk] = run;
        }
    }
}

// ---------------- bucket scatter: packed (ln<<17|src) -> inter ----------------
__global__ __launch_bounds__(256) void k_bscatter(const int* __restrict__ src,
                                                  const int* __restrict__ dst,
                                                  int* __restrict__ bcur,
                                                  uint32* __restrict__ inter, int e) {
    __shared__ int cnt[MAXBUK];
    __shared__ int run[MAXBUK];
    int per = (e + gridDim.x - 1) / gridDim.x;
    int lo = blockIdx.x * per, hi = min(lo + per, e);
    for (int i = threadIdx.x; i < MAXBUK; i += 256) cnt[i] = 0;
    __syncthreads();
    for (int i = lo + threadIdx.x; i < hi; i += 256)
        atomicAdd(&cnt[dst[i] >> BSHIFT], 1);
    __syncthreads();
    if (threadIdx.x < MAXBUK) {
        int c = cnt[threadIdx.x];
        run[threadIdx.x] = c ? atomicAdd(&bcur[threadIdx.x], c) : 0;
        cnt[threadIdx.x] = 0;
    }
    __syncthreads();
    for (int i = lo + threadIdx.x; i < hi; i += 256) {
        int d = dst[i];
        int s = src[i];
        int b = d >> BSHIFT;
        int ln = d & ((1 << BSHIFT) - 1);
        int pos = run[b] + atomicAdd(&cnt[b], 1);
        inter[pos] = ((uint32)ln << 17) | (uint32)s;
    }
}

// ---------------- per-bucket CSR build ----------------
__global__ __launch_bounds__(256) void k_build(const uint32* __restrict__ inter,
                                               const int* __restrict__ bbase,
                                               int* __restrict__ rowptr,
                                               float* __restrict__ dinv,
                                               int* __restrict__ csr,
                                               int n, int nbuk) {
    __shared__ int cnt[1024];
    __shared__ int scn[1024];
    __shared__ int part[256];
    __shared__ int stage[CAP];
    int b = blockIdx.x;
    int t = threadIdx.x;
    int nlo = b << BSHIFT;
    int nhi = min(nlo + 1024, n);
    int nn = nhi - nlo;
    int e0 = bbase[b], e1 = bbase[b + 1];
    int ne = e1 - e0;
    for (int i = t; i < nn; i += 256) cnt[i] = 0;
    __syncthreads();
    for (int i = t; i < ne; i += 256)
        atomicAdd(&cnt[inter[e0 + i] >> 17], 1);
    __syncthreads();
    int base4 = 4 * t;
    int sum = 0;
    for (int j = 0; j < 4; ++j) {
        int idx = base4 + j;
        int v = (idx < nn) ? cnt[idx] : 0;
        if (idx < nn) scn[idx] = sum;
        sum += v;
    }
    part[t] = sum;
    __syncthreads();
    for (int off = 1; off < 256; off <<= 1) {
        int v = (t >= off) ? part[t - off] : 0;
        __syncthreads();
        part[t] += v;
        __syncthreads();
    }
    int pbase = (t == 0) ? 0 : part[t - 1];
    for (int j = 0; j < 4; ++j) {
        int idx = base4 + j;
        if (idx < nn) scn[idx] += pbase;
    }
    __syncthreads();
    for (int i = t; i < nn; i += 256) {
        rowptr[nlo + i] = e0 + scn[i];
        dinv[nlo + i] = rsqrtf((float)cnt[i] + 1.0f);
    }
    if (b == 0 && t == 0) rowptr[n] = bbase[nbuk];
    for (int i = t; i < nn; i += 256) cnt[i] = 0;
    __syncthreads();
    for (int i = t; i < ne; i += 256) {
        uint32 p = inter[e0 + i];
        int ln = p >> 17;
        int s = p & 0x1FFFF;
        int pos = scn[ln] + atomicAdd(&cnt[ln], 1);
        if (pos < CAP) stage[pos] = s;
        else csr[e0 + pos] = s;
    }
    __syncthreads();
    int m = min(ne, CAP);
    for (int i = t; i < m; i += 256) csr[e0 + i] = stage[i];  // coalesced
}

// ---------------- MFMA GEMM (layer 1): Y(bf16) = (X f32 @ W) * dinv[row] ----------------
__global__ __launch_bounds__(256) void k_gemm_mfma(const float* __restrict__ Xv,
                                                   const uint32* __restrict__ Wb,
                                                   const float* __restrict__ dinv,
                                                   uint32* __restrict__ Y, int n) {
    int lane = threadIdx.x & 63;
    int wave = threadIdx.x >> 6;
    int l15 = lane & 15;
    int grp = lane >> 4;  // 0..3
    ABFrag bf[4][2];
    const uint4* Wb4 = (const uint4*)Wb;
#pragma unroll
    for (int ct = 0; ct < 4; ++ct)
#pragma unroll
        for (int ks = 0; ks < 2; ++ks)
            bf[ct][ks].q = Wb4[(ct * 2 + ks) * 64 + lane];

    int rbase0 = blockIdx.x * 128 + wave * 32;
    f32x4 acc[2][4] = {};
#pragma unroll
    for (int sub = 0; sub < 2; ++sub) {
        int row = min(rbase0 + sub * 16 + l15, n - 1);
        ABFrag a[2];
        const float4* X4 = (const float4*)Xv;
#pragma unroll
        for (int ks = 0; ks < 2; ++ks) {
            float4 f0 = X4[(size_t)row * 16 + ks * 8 + grp * 2];
            float4 f1 = X4[(size_t)row * 16 + ks * 8 + grp * 2 + 1];
            a[ks].u[0] = packbf16(f0.x, f0.y);
            a[ks].u[1] = packbf16(f0.z, f0.w);
            a[ks].u[2] = packbf16(f1.x, f1.y);
            a[ks].u[3] = packbf16(f1.z, f1.w);
        }
#pragma unroll
        for (int ct = 0; ct < 4; ++ct) {
            acc[sub][ct] = __builtin_amdgcn_mfma_f32_16x16x32_bf16(a[0].v, bf[ct][0].v,
                                                                   acc[sub][ct], 0, 0, 0);
            acc[sub][ct] = __builtin_amdgcn_mfma_f32_16x16x32_bf16(a[1].v, bf[ct][1].v,
                                                                   acc[sub][ct], 0, 0, 0);
        }
    }
#pragma unroll
    for (int sub = 0; sub < 2; ++sub) {
        int rb = rbase0 + sub * 16;
#pragma unroll
        for (int r = 0; r < 4; ++r) {
            int row = rb + grp * 4 + r;
            float dd = dinv[min(row, n - 1)];
#pragma unroll
            for (int ct = 0; ct < 4; ++ct) {
                float v = acc[sub][ct][r] * dd;
                float w = __shfl_xor(v, 1);
                if (!(lane & 1) && row < n)
                    Y[(size_t)row * 32 + ct * 8 + (l15 >> 1)] = packbf16(v, w);
            }
        }
    }
}

// ---------------- agg1 + FUSED gemm2: y2 = (relu(dinv*(agg)+b1)) @ W2 * dinv ----------------
// Block = 8 nodes. Phase 1 (r14 gather structure): h1 rows -> LDS (fp32, unrounded).
// Phase 2: block-wide 8x64 @ 64x64 VALU GEMM from LDS (W2 staged in LDS), write y2 bf16.
__global__ __launch_bounds__(256) void k_agg_gemm(const uint32* __restrict__ h,
                                                  const int* __restrict__ csrs,
                                                  const int* __restrict__ rowptr,
                                                  const float* __restrict__ dinv,
                                                  const float* __restrict__ b1,
                                                  const float* __restrict__ W2,
                                                  uint32* __restrict__ y2, int n) {
    __shared__ float h1s[8][64];
    __shared__ float w2s[64][64];
    int tid = threadIdx.x;
    int wave = tid >> 6;
    int lane = tid & 63;
    int half = lane >> 5;
    int hl = lane & 31;
    int grp = hl >> 3;   // edge-group (0..3)
    int sub = hl & 7;    // uint4 index within 128B row
    int slot = wave * 2 + half;
    int nb = blockIdx.x * 8;
    int node = nb + slot;
    bool active = node < n;

    // stage W2 into LDS (coalesced float4), consumed after the barrier below
    {
        const float4* W24 = (const float4*)W2;
        float4* w2s4 = (float4*)&w2s[0][0];
        for (int i = tid; i < 1024; i += 256) w2s4[i] = W24[i];
    }

    const uint4* h4 = (const uint4*)h;
    float acc[8] = {};
    int r0 = 0, r1 = 0;
    if (active) { r0 = rowptr[node]; r1 = rowptr[node + 1]; }
    int m = r1 - 1;
    for (int e = r0; e < r1; e += 16) {
        int eA = min(e + grp, m),      eB = min(e + 4 + grp, m);
        int eC = min(e + 8 + grp, m),  eD = min(e + 12 + grp, m);
        int sA = csrs[eA];
        int sB = csrs[eB];
        int sC = csrs[eC];
        int sD = csrs[eD];
        uint4 gA = h4[(size_t)sA * 8 + sub];
        uint4 gB = h4[(size_t)sB * 8 + sub];
        uint4 gC = h4[(size_t)sC * 8 + sub];
        uint4 gD = h4[(size_t)sD * 8 + sub];
        if (e + grp > m)      { gA.x = gA.y = gA.z = gA.w = 0u; }
        if (e + 4 + grp > m)  { gB.x = gB.y = gB.z = gB.w = 0u; }
        if (e + 8 + grp > m)  { gC.x = gC.y = gC.z = gC.w = 0u; }
        if (e + 12 + grp > m) { gD.x = gD.y = gD.z = gD.w = 0u; }
        acc[0] += bf16lo(gA.x) + bf16lo(gB.x) + bf16lo(gC.x) + bf16lo(gD.x);
        acc[1] += bf16hi(gA.x) + bf16hi(gB.x) + bf16hi(gC.x) + bf16hi(gD.x);
        acc[2] += bf16lo(gA.y) + bf16lo(gB.y) + bf16lo(gC.y) + bf16lo(gD.y);
        acc[3] += bf16hi(gA.y) + bf16hi(gB.y) + bf16hi(gC.y) + bf16hi(gD.y);
        acc[4] += bf16lo(gA.z) + bf16lo(gB.z) + bf16lo(gC.z) + bf16lo(gD.z);
        acc[5] += bf16hi(gA.z) + bf16hi(gB.z) + bf16hi(gC.z) + bf16hi(gD.z);
        acc[6] += bf16lo(gA.w) + bf16lo(gB.w) + bf16lo(gC.w) + bf16lo(gD.w);
        acc[7] += bf16hi(gA.w) + bf16hi(gB.w) + bf16hi(gC.w) + bf16hi(gD.w);
    }
#pragma unroll
    for (int c = 0; c < 8; ++c) {
        acc[c] += __shfl_xor(acc[c], 8);
        acc[c] += __shfl_xor(acc[c], 16);
    }
    if (active && grp == 0) {
        uint4 sv = h4[(size_t)node * 8 + sub];
        float dd = dinv[node];
        float o0 = (acc[0] + bf16lo(sv.x)) * dd + b1[hl * 8 + 0];
        float o1 = (acc[1] + bf16hi(sv.x)) * dd + b1[hl * 8 + 1];
        float o2 = (acc[2] + bf16lo(sv.y)) * dd + b1[hl * 8 + 2];
        float o3 = (acc[3] + bf16hi(sv.y)) * dd + b1[hl * 8 + 3];
        float o4 = (acc[4] + bf16lo(sv.z)) * dd + b1[hl * 8 + 4];
        float o5 = (acc[5] + bf16hi(sv.z)) * dd + b1[hl * 8 + 5];
        float o6 = (acc[6] + bf16lo(sv.w)) * dd + b1[hl * 8 + 6];
        float o7 = (acc[7] + bf16hi(sv.w)) * dd + b1[hl * 8 + 7];
        h1s[slot][hl * 8 + 0] = o0 > 0.f ? o0 : 0.f;
        h1s[slot][hl * 8 + 1] = o1 > 0.f ? o1 : 0.f;
        h1s[slot][hl * 8 + 2] = o2 > 0.f ? o2 : 0.f;
        h1s[slot][hl * 8 + 3] = o3 > 0.f ? o3 : 0.f;
        h1s[slot][hl * 8 + 4] = o4 > 0.f ? o4 : 0.f;
        h1s[slot][hl * 8 + 5] = o5 > 0.f ? o5 : 0.f;
        h1s[slot][hl * 8 + 6] = o6 > 0.f ? o6 : 0.f;
        h1s[slot][hl * 8 + 7] = o7 > 0.f ? o7 : 0.f;
    }
    __syncthreads();
    // phase 2: y2[r][2q..2q+1] = h1s[r][:] @ w2s[:][2q..2q+1], scaled by dinv[row]
    {
        int r = tid >> 5;      // 0..7
        int q = tid & 31;      // packed-channel pair index
        int row = nb + r;
        if (row < n) {
            float a0 = 0.f, a1 = 0.f;
#pragma unroll
            for (int k = 0; k < 64; ++k) {
                float hv = h1s[r][k];                       // broadcast
                const float2* wrow = (const float2*)w2s[k];
                float2 wv = wrow[q];
                a0 += hv * wv.x;
                a1 += hv * wv.y;
            }
            float dd = dinv[row];
            y2[(size_t)row * 32 + q] = packbf16(a0 * dd, a1 * dd);
        }
    }
}

// ---------------- agg2 + pool: pooled[g] += relu(dinv*(agg y2)+b2) ----------------
__global__ __launch_bounds__(256) void k_aggregate2(const uint32* __restrict__ h,
                                                    const int* __restrict__ csrs,
                                                    const int* __restrict__ rowptr,
                                                    const float* __restrict__ dinv,
                                                    const float* __restrict__ b,
                                                    const int* __restrict__ batch,
                                                    float* __restrict__ pooled, int n) {
    __shared__ float red[8][64];
    __shared__ int sg[8];
    int tid = threadIdx.x;
    int wave = tid >> 6;
    int lane = tid & 63;
    int half = lane >> 5;
    int hl = lane & 31;
    int grp = hl >> 3;
    int sub = hl & 7;
    int slot = wave * 2 + half;
    int node = blockIdx.x * 8 + slot;
    bool active = node < n;
    const uint4* h4 = (const uint4*)h;
    float acc[8] = {};
    int r0 = 0, r1 = 0;
    if (active) { r0 = rowptr[node]; r1 = rowptr[node + 1]; }
    int m = r1 - 1;
    for (int e = r0; e < r1; e += 16) {
        int eA = min(e + grp, m),      eB = min(e + 4 + grp, m);
        int eC = min(e + 8 + grp, m),  eD = min(e + 12 + grp, m);
        int sA = csrs[eA];
        int sB = csrs[eB];
        int sC = csrs[eC];
        int sD = csrs[eD];
        uint4 gA = h4[(size_t)sA * 8 + sub];
        uint4 gB = h4[(size_t)sB * 8 + sub];
        uint4 gC = h4[(size_t)sC * 8 + sub];
        uint4 gD = h4[(size_t)sD * 8 + sub];
        if (e + grp > m)      { gA.x = gA.y = gA.z = gA.w = 0u; }
        if (e + 4 + grp > m)  { gB.x = gB.y = gB.z = gB.w = 0u; }
        if (e + 8 + grp > m)  { gC.x = gC.y = gC.z = gC.w = 0u; }
        if (e + 12 + grp > m) { gD.x = gD.y = gD.z = gD.w = 0u; }
        acc[0] += bf16lo(gA.x) + bf16lo(gB.x) + bf16lo(gC.x) + bf16lo(gD.x);
        acc[1] += bf16hi(gA.x) + bf16hi(gB.x) + bf16hi(gC.x) + bf16hi(gD.x);
        acc[2] += bf16lo(gA.y) + bf16lo(gB.y) + bf16lo(gC.y) + bf16lo(gD.y);
        acc[3] += bf16hi(gA.y) + bf16hi(gB.y) + bf16hi(gC.y) + bf16hi(gD.y);
        acc[4] += bf16lo(gA.z) + bf16lo(gB.z) + bf16lo(gC.z) + bf16lo(gD.z);
        acc[5] += bf16hi(gA.z) + bf16hi(gB.z) + bf16hi(gC.z) + bf16hi(gD.z);
        acc[6] += bf16lo(gA.w) + bf16lo(gB.w) + bf16lo(gC.w) + bf16lo(gD.w);
        acc[7] += bf16hi(gA.w) + bf16hi(gB.w) + bf16hi(gC.w) + bf16hi(gD.w);
    }
#pragma unroll
    for (int c = 0; c < 8; ++c) {
        acc[c] += __shfl_xor(acc[c], 8);
        acc[c] += __shfl_xor(acc[c], 16);
    }
    if (grp == 0) {
        float o[8] = {};
        if (active) {
            uint4 sv = h4[(size_t)node * 8 + sub];
            float dd = dinv[node];
            o[0] = (acc[0] + bf16lo(sv.x)) * dd + b[hl * 8 + 0];
            o[1] = (acc[1] + bf16hi(sv.x)) * dd + b[hl * 8 + 1];
            o[2] = (acc[2] + bf16lo(sv.y)) * dd + b[hl * 8 + 2];
            o[3] = (acc[3] + bf16hi(sv.y)) * dd + b[hl * 8 + 3];
            o[4] = (acc[4] + bf16lo(sv.z)) * dd + b[hl * 8 + 4];
            o[5] = (acc[5] + bf16hi(sv.z)) * dd + b[hl * 8 + 5];
            o[6] = (acc[6] + bf16lo(sv.w)) * dd + b[hl * 8 + 6];
            o[7] = (acc[7] + bf16hi(sv.w)) * dd + b[hl * 8 + 7];
#pragma unroll
            for (int c = 0; c < 8; ++c) o[c] = o[c] > 0.f ? o[c] : 0.f;
        }
#pragma unroll
        for (int c = 0; c < 8; ++c) red[slot][hl * 8 + c] = o[c];
    }
    if (hl == 0) sg[slot] = active ? batch[node] : -1;
    __syncthreads();
    if (wave == 0) {
        float s = red[0][lane];
        int gcur = sg[0];
        for (int w = 1; w < 8; ++w) {
            int gw = sg[w];
            if (gw < 0) break;
            if (gw == gcur) {
                s += red[w][lane];
            } else {
                if (gcur >= 0) atomicAdd(&pooled[gcur * H + lane], s);
                s = red[w][lane];
                gcur = gw;
            }
        }
        if (gcur >= 0) atomicAdd(&pooled[gcur * H + lane], s);
    }
}

// ---------------- final linear ----------------
__global__ void k_final(const float* __restrict__ pooled, const float* __restrict__ gf,
                        const float* __restrict__ Wlin, const float* __restrict__ blin,
                        float* __restrict__ out) {
    int t = threadIdx.x;
    if (t >= G * OUT) return;
    int g = t >> 1, o = t & 1;
    float acc = blin[o];
#pragma unroll
    for (int j = 0; j < 64; ++j) acc += pooled[g * H + j] * Wlin[j * OUT + o];
    acc += gf[g] * Wlin[64 * OUT + o];
    out[g * OUT + o] = acc;
}

extern "C" void kernel_launch(void* const* d_in, const int* in_sizes, int n_in,
                              void* d_out, int out_size, void* d_ws, size_t ws_size,
                              hipStream_t stream) {
    const float* x          = (const float*)d_in[0];
    const int*   edge_index = (const int*)d_in[1];
    const int*   batch      = (const int*)d_in[2];
    const float* gf         = (const float*)d_in[3];
    const float* W1         = (const float*)d_in[4];
    const float* b1         = (const float*)d_in[5];
    const float* W2         = (const float*)d_in[6];
    const float* b2         = (const float*)d_in[7];
    const float* Wlin       = (const float*)d_in[8];
    const float* blin       = (const float*)d_in[9];
    float* out = (float*)d_out;

    const int N = in_sizes[0] / H;
    const int E = in_sizes[1] / 2;
    const int* src = edge_index;
    const int* dst = edge_index + E;
    const int NBUK = (N + (1 << BSHIFT) - 1) >> BSHIFT;  // 98 for N=100k (<=MAXBUK)

    // workspace layout
    float* ws = (float*)d_ws;
    float* dinv   = ws;                         // N
    uint32* bufA  = (uint32*)(dinv + N);        // N*32 uints (bf16 packed), 16B-aligned
    uint32* bufB  = bufA + (size_t)N * 32;      // N*32 uints
    float* pooled = (float*)(bufB + (size_t)N * 32);  // G*H
    int*   rowptr = (int*)(pooled + G * H);     // N+1
    int*   bcnt   = rowptr + (N + 1);           // MAXBUK
    int*   bbase  = bcnt + MAXBUK;              // MAXBUK+1
    int*   bcur   = bbase + (MAXBUK + 1);       // MAXBUK
    int*   done   = bcur + MAXBUK;              // 1
    size_t off = (size_t)(done + 1 - (int*)d_ws);
    off = (off + 3) & ~(size_t)3;               // 16B align
    uint32* Wb   = (uint32*)d_ws + off;         // 2048 uints (W1 B-frags)
    int*   csrs  = (int*)(Wb + 2048);           // E ints
    uint32* inter = (uint32*)(csrs + E);        // E uints (packed ln<<17|src)

    const int T = 256;

    // setup + CSR build
    k_setup<<<2, T, 0, stream>>>(W1, Wb, pooled, bcnt, done);
    k_bhist<<<256, T, 0, stream>>>(dst, bcnt, bbase, bcur, done, E, NBUK);
    k_bscatter<<<128, T, 0, stream>>>(src, dst, bcur, inter, E);
    k_build<<<NBUK, T, 0, stream>>>(inter, bbase, rowptr, dinv, csrs, N, NBUK);

    // layer 1 GEMM (MFMA)
    k_gemm_mfma<<<(N + 127) / 128, T, 0, stream>>>(x, Wb, dinv, bufA, N);

    // agg1 + fused gemm2 -> y2 (bufB)
    k_agg_gemm<<<(N + 7) / 8, T, 0, stream>>>(bufA, csrs, rowptr, dinv, b1, W2,
                                              bufB, N);

    // agg2 + pool
    k_aggregate2<<<(N + 7) / 8, T, 0, stream>>>(bufB, csrs, rowptr, dinv, b2, batch,
                                                pooled, N);

    // head
    k_final<<<1, 128, 0, stream>>>(pooled, gf, Wlin, blin, out);
}

// Round 17
// 170.643 us; speedup vs baseline: 1.0503x; 1.0503x over previous
//
#include <hip/hip_runtime.h>

#define H 64
#define G 64
#define OUT 2
#define MAXBUK 128
#define BSHIFT 10
#define CAP 12288

typedef unsigned int uint32;
using short8 = __attribute__((ext_vector_type(8))) short;
using f32x4  = __attribute__((ext_vector_type(4))) float;

union ABFrag { uint32 u[4]; uint4 q; short8 v; };

__device__ inline float bf16lo(uint32 u) { return __uint_as_float(u << 16); }
__device__ inline float bf16hi(uint32 u) { return __uint_as_float(u & 0xffff0000u); }
__device__ inline uint32 packbf16(float a, float b) {
    uint32 ua = __float_as_uint(a);
    uint32 ub = __float_as_uint(b);
    ua = (ua + 0x7fffu + ((ua >> 16) & 1u)) >> 16;                 // RNE
    ub = (ub + 0x7fffu + ((ub >> 16) & 1u)) & 0xffff0000u;         // RNE
    return ua | ub;
}

// ---------------- fused setup: prepW(W1,W2) + zero pooled/bcnt/done ----------------
__global__ __launch_bounds__(256) void k_setup(const float* __restrict__ W1,
                                               const float* __restrict__ W2,
                                               uint32* __restrict__ Wb,
                                               float* __restrict__ pooled,
                                               int* __restrict__ bcnt,
                                               int* __restrict__ done) {
    int blk = blockIdx.x;
    int t = threadIdx.x;
    if (blk < 2) {
        const float* W = blk ? W2 : W1;
        uint32* dw = Wb + blk * 2048;
        for (int i = t; i < 2048; i += 256) {
            int r = i & 3;
            int lane = (i >> 2) & 63;
            int slot = i >> 8;
            int ct = slot >> 1, ks = slot & 1;
            int col = ct * 16 + (lane & 15);
            int k0 = ks * 32 + (lane >> 4) * 8;
            float a = W[(k0 + 2 * r) * 64 + col];
            float b = W[(k0 + 2 * r + 1) * 64 + col];
            dw[i] = packbf16(a, b);
        }
    } else {
        for (int i = t; i < G * H; i += 256) pooled[i] = 0.0f;
        if (t < MAXBUK) bcnt[t] = 0;
        if (t == 0) *done = 0;
    }
}

// ---------------- bucket histogram + fused last-block scan ----------------
__global__ __launch_bounds__(256) void k_bhist(const int* __restrict__ dst,
                                               int* __restrict__ bcnt,
                                               int* __restrict__ bbase,
                                               int* __restrict__ bcur,
                                               int* __restrict__ done,
                                               int e, int nbuk) {
    __shared__ int hh[MAXBUK];
    for (int i = threadIdx.x; i < MAXBUK; i += 256) hh[i] = 0;
    __syncthreads();
    int stride = gridDim.x * 256;
    for (int i = blockIdx.x * 256 + threadIdx.x; i < e; i += stride)
        atomicAdd(&hh[__builtin_nontemporal_load(&dst[i]) >> BSHIFT], 1);
    __syncthreads();
    for (int i = threadIdx.x; i < nbuk; i += 256)
        if (hh[i]) atomicAdd(&bcnt[i], hh[i]);
    // last finishing block performs the (tiny) serial scan
    if (threadIdx.x == 0) {
        __threadfence();
        int ticket = atomicAdd(done, 1);
        if (ticket == (int)gridDim.x - 1) {
            int run = 0;
            for (int i = 0; i < nbuk; ++i) {
                int c = atomicAdd(&bcnt[i], 0);  // coherent read
                bbase[i] = run; bcur[i] = run; run += c;
            }
            bbase[nbuk] = run;
        }
    }
}

// ---------------- bucket scatter: packed (ln<<17|src) -> inter, contiguous runs ----------------
__global__ __launch_bounds__(256) void k_bscatter(const int* __restrict__ src,
                                                  const int* __restrict__ dst,
                                                  int* __restrict__ bcur,
                                                  uint32* __restrict__ inter, int e) {
    __shared__ int cnt[MAXBUK];
    __shared__ int run[MAXBUK];
    int per = (e + gridDim.x - 1) / gridDim.x;
    int lo = blockIdx.x * per, hi = min(lo + per, e);
    for (int i = threadIdx.x; i < MAXBUK; i += 256) cnt[i] = 0;
    __syncthreads();
    for (int i = lo + threadIdx.x; i < hi; i += 256)
        atomicAdd(&cnt[dst[i] >> BSHIFT], 1);
    __syncthreads();
    if (threadIdx.x < MAXBUK) {
        int c = cnt[threadIdx.x];
        run[threadIdx.x] = c ? atomicAdd(&bcur[threadIdx.x], c) : 0;
        cnt[threadIdx.x] = 0;
    }
    __syncthreads();
    for (int i = lo + threadIdx.x; i < hi; i += 256) {
        int d = dst[i];
        int s = src[i];
        int b = d >> BSHIFT;
        int ln = d & ((1 << BSHIFT) - 1);
        int pos = run[b] + atomicAdd(&cnt[b], 1);
        inter[pos] = ((uint32)ln << 17) | (uint32)s;
    }
}

// ---------------- per-bucket CSR build ----------------
__global__ __launch_bounds__(256) void k_build(const uint32* __restrict__ inter,
                                               const int* __restrict__ bbase,
                                               int* __restrict__ rowptr,
                                               float* __restrict__ dinv,
                                               int* __restrict__ csr,
                                               int n, int nbuk) {
    __shared__ int cnt[1024];
    __shared__ int scn[1024];
    __shared__ int part[256];
    __shared__ int stage[CAP];
    int b = blockIdx.x;
    int t = threadIdx.x;
    int nlo = b << BSHIFT;
    int nhi = min(nlo + 1024, n);
    int nn = nhi - nlo;
    int e0 = bbase[b], e1 = bbase[b + 1];
    int ne = e1 - e0;
    for (int i = t; i < nn; i += 256) cnt[i] = 0;
    __syncthreads();
    for (int i = t; i < ne; i += 256)
        atomicAdd(&cnt[inter[e0 + i] >> 17], 1);
    __syncthreads();
    int base4 = 4 * t;
    int sum = 0;
    for (int j = 0; j < 4; ++j) {
        int idx = base4 + j;
        int v = (idx < nn) ? cnt[idx] : 0;
        if (idx < nn) scn[idx] = sum;
        sum += v;
    }
    part[t] = sum;
    __syncthreads();
    for (int off = 1; off < 256; off <<= 1) {
        int v = (t >= off) ? part[t - off] : 0;
        __syncthreads();
        part[t] += v;
        __syncthreads();
    }
    int pbase = (t == 0) ? 0 : part[t - 1];
    for (int j = 0; j < 4; ++j) {
        int idx = base4 + j;
        if (idx < nn) scn[idx] += pbase;
    }
    __syncthreads();
    for (int i = t; i < nn; i += 256) {
        rowptr[nlo + i] = e0 + scn[i];
        dinv[nlo + i] = rsqrtf((float)cnt[i] + 1.0f);
    }
    if (b == 0 && t == 0) rowptr[n] = bbase[nbuk];
    for (int i = t; i < nn; i += 256) cnt[i] = 0;
    __syncthreads();
    for (int i = t; i < ne; i += 256) {
        uint32 p = inter[e0 + i];
        int ln = p >> 17;
        int s = p & 0x1FFFF;
        int pos = scn[ln] + atomicAdd(&cnt[ln], 1);
        if (pos < CAP) stage[pos] = s;
        else csr[e0 + pos] = s;
    }
    __syncthreads();
    int m = min(ne, CAP);
    for (int i = t; i < m; i += 256) csr[e0 + i] = stage[i];  // coalesced
}

// ---------------- MFMA GEMM: Y(bf16,[n,64]) = (X[n,64] @ W) * dinv[row] ----------------
template <int BFIN>
__global__ __launch_bounds__(256) void k_gemm_mfma(const void* __restrict__ Xv,
                                                   const uint32* __restrict__ Wb,
                                                   const float* __restrict__ dinv,
                                                   uint32* __restrict__ Y, int n) {
    int lane = threadIdx.x & 63;
    int wave = threadIdx.x >> 6;
    int l15 = lane & 15;
    int grp = lane >> 4;  // 0..3
    ABFrag bf[4][2];
    const uint4* Wb4 = (const uint4*)Wb;
#pragma unroll
    for (int ct = 0; ct < 4; ++ct)
#pragma unroll
        for (int ks = 0; ks < 2; ++ks)
            bf[ct][ks].q = Wb4[(ct * 2 + ks) * 64 + lane];

    int rbase0 = blockIdx.x * 128 + wave * 32;
    f32x4 acc[2][4] = {};
#pragma unroll
    for (int sub = 0; sub < 2; ++sub) {
        int row = min(rbase0 + sub * 16 + l15, n - 1);
        ABFrag a[2];
        if (BFIN) {
            const uint4* X4 = (const uint4*)Xv;
#pragma unroll
            for (int ks = 0; ks < 2; ++ks)
                a[ks].q = X4[(size_t)row * 8 + ks * 4 + grp];
        } else {
            const float4* X4 = (const float4*)Xv;
#pragma unroll
            for (int ks = 0; ks < 2; ++ks) {
                float4 f0 = X4[(size_t)row * 16 + ks * 8 + grp * 2];
                float4 f1 = X4[(size_t)row * 16 + ks * 8 + grp * 2 + 1];
                a[ks].u[0] = packbf16(f0.x, f0.y);
                a[ks].u[1] = packbf16(f0.z, f0.w);
                a[ks].u[2] = packbf16(f1.x, f1.y);
                a[ks].u[3] = packbf16(f1.z, f1.w);
            }
        }
#pragma unroll
        for (int ct = 0; ct < 4; ++ct) {
            acc[sub][ct] = __builtin_amdgcn_mfma_f32_16x16x32_bf16(a[0].v, bf[ct][0].v,
                                                                   acc[sub][ct], 0, 0, 0);
            acc[sub][ct] = __builtin_amdgcn_mfma_f32_16x16x32_bf16(a[1].v, bf[ct][1].v,
                                                                   acc[sub][ct], 0, 0, 0);
        }
    }
#pragma unroll
    for (int sub = 0; sub < 2; ++sub) {
        int rb = rbase0 + sub * 16;
#pragma unroll
        for (int r = 0; r < 4; ++r) {
            int row = rb + grp * 4 + r;
            float dd = dinv[min(row, n - 1)];
#pragma unroll
            for (int ct = 0; ct < 4; ++ct) {
                float v = acc[sub][ct][r] * dd;
                float w = __shfl_xor(v, 1);
                if (!(lane & 1) && row < n)
                    Y[(size_t)row * 32 + ct * 8 + (l15 >> 1)] = packbf16(v, w);
            }
        }
    }
}

// ---------------- fused aggregate: wide uint4 gathers, 4 edges per instruction ----------------
// one node per HALF-wave; lane = (edge-group grp 0..3) x (row-quarter sub 0..7).
// batch-16 edges = 4 gather instructions; shfl-reduce groups at end.
template <int DOPOOL>
__global__ __launch_bounds__(256) void k_aggregate(const uint32* __restrict__ h,
                                                   const int* __restrict__ csrs,
                                                   const int* __restrict__ rowptr,
                                                   const float* __restrict__ dinv,
                                                   const float* __restrict__ b,
                                                   const int* __restrict__ batch,
                                                   uint32* __restrict__ hout,
                                                   float* __restrict__ pooled, int n) {
    __shared__ float red[8][64];
    __shared__ int sg[8];
    int tid = threadIdx.x;
    int wave = tid >> 6;
    int lane = tid & 63;
    int half = lane >> 5;
    int hl = lane & 31;
    int grp = hl >> 3;   // edge within gather instruction (0..3)
    int sub = hl & 7;    // uint4 index within 128B row (0..7)
    int slot = wave * 2 + half;
    int node = blockIdx.x * 8 + slot;
    bool active = node < n;
    const uint4* h4 = (const uint4*)h;
    float acc[8] = {};
    float o[8] = {};
    if (active) {
        int r0 = rowptr[node];
        int r1 = rowptr[node + 1];
        int m = r1 - 1;
        for (int e = r0; e < r1; e += 16) {
            int eA = e + grp, eB = e + 4 + grp, eC = e + 8 + grp, eD = e + 12 + grp;
            int sA = csrs[min(eA, m)];
            int sB = csrs[min(eB, m)];
            int sC = csrs[min(eC, m)];
            int sD = csrs[min(eD, m)];
            uint4 gA = h4[(size_t)sA * 8 + sub];
            uint4 gB = h4[(size_t)sB * 8 + sub];
            uint4 gC = h4[(size_t)sC * 8 + sub];
            uint4 gD = h4[(size_t)sD * 8 + sub];
            if (eA > m) { gA.x = gA.y = gA.z = gA.w = 0u; }
            if (eB > m) { gB.x = gB.y = gB.z = gB.w = 0u; }
            if (eC > m) { gC.x = gC.y = gC.z = gC.w = 0u; }
            if (eD > m) { gD.x = gD.y = gD.z = gD.w = 0u; }
            acc[0] += bf16lo(gA.x) + bf16lo(gB.x) + bf16lo(gC.x) + bf16lo(gD.x);
            acc[1] += bf16hi(gA.x) + bf16hi(gB.x) + bf16hi(gC.x) + bf16hi(gD.x);
            acc[2] += bf16lo(gA.y) + bf16lo(gB.y) + bf16lo(gC.y) + bf16lo(gD.y);
            acc[3] += bf16hi(gA.y) + bf16hi(gB.y) + bf16hi(gC.y) + bf16hi(gD.y);
            acc[4] += bf16lo(gA.z) + bf16lo(gB.z) + bf16lo(gC.z) + bf16lo(gD.z);
            acc[5] += bf16hi(gA.z) + bf16hi(gB.z) + bf16hi(gC.z) + bf16hi(gD.z);
            acc[6] += bf16lo(gA.w) + bf16lo(gB.w) + bf16lo(gC.w) + bf16lo(gD.w);
            acc[7] += bf16hi(gA.w) + bf16hi(gB.w) + bf16hi(gC.w) + bf16hi(gD.w);
        }
        // reduce the 4 edge-groups (lanes sub, sub+8, sub+16, sub+24 of this half)
#pragma unroll
        for (int c = 0; c < 8; ++c) {
            acc[c] += __shfl_xor(acc[c], 8);
            acc[c] += __shfl_xor(acc[c], 16);
        }
        // self term + epilogue on lanes grp==0 (hl = sub = 0..7)
        uint4 sv = h4[(size_t)node * 8 + sub];
        float dd = dinv[node];
        if (grp == 0) {
            float s0 = bf16lo(sv.x), s1 = bf16hi(sv.x);
            float s2 = bf16lo(sv.y), s3 = bf16hi(sv.y);
            float s4 = bf16lo(sv.z), s5 = bf16hi(sv.z);
            float s6 = bf16lo(sv.w), s7 = bf16hi(sv.w);
            o[0] = (acc[0] + s0) * dd + b[hl * 8 + 0];
            o[1] = (acc[1] + s1) * dd + b[hl * 8 + 1];
            o[2] = (acc[2] + s2) * dd + b[hl * 8 + 2];
            o[3] = (acc[3] + s3) * dd + b[hl * 8 + 3];
            o[4] = (acc[4] + s4) * dd + b[hl * 8 + 4];
            o[5] = (acc[5] + s5) * dd + b[hl * 8 + 5];
            o[6] = (acc[6] + s6) * dd + b[hl * 8 + 6];
            o[7] = (acc[7] + s7) * dd + b[hl * 8 + 7];
#pragma unroll
            for (int c = 0; c < 8; ++c) o[c] = o[c] > 0.f ? o[c] : 0.f;
            if (!DOPOOL) {
                uint4 u;
                u.x = packbf16(o[0], o[1]);
                u.y = packbf16(o[2], o[3]);
                u.z = packbf16(o[4], o[5]);
                u.w = packbf16(o[6], o[7]);
                ((uint4*)hout)[(size_t)node * 8 + hl] = u;
            }
        }
    }
    if (DOPOOL) {
        if (grp == 0) {
#pragma unroll
            for (int c = 0; c < 8; ++c)
                red[slot][hl * 8 + c] = active ? o[c] : 0.f;
        }
        if (hl == 0) sg[slot] = active ? batch[node] : -1;
        __syncthreads();
        if (wave == 0) {
            float s = red[0][lane];
            int gcur = sg[0];
            for (int w = 1; w < 8; ++w) {
                int gw = sg[w];
                if (gw < 0) break;
                if (gw == gcur) {
                    s += red[w][lane];
                } else {
                    if (gcur >= 0) atomicAdd(&pooled[gcur * H + lane], s);
                    s = red[w][lane];
                    gcur = gw;
                }
            }
            if (gcur >= 0) atomicAdd(&pooled[gcur * H + lane], s);
        }
    }
}

// ---------------- final linear ----------------
__global__ void k_final(const float* __restrict__ pooled, const float* __restrict__ gf,
                        const float* __restrict__ Wlin, const float* __restrict__ blin,
                        float* __restrict__ out) {
    int t = threadIdx.x;
    if (t >= G * OUT) return;
    int g = t >> 1, o = t & 1;
    float acc = blin[o];
#pragma unroll
    for (int j = 0; j < 64; ++j) acc += pooled[g * H + j] * Wlin[j * OUT + o];
    acc += gf[g] * Wlin[64 * OUT + o];
    out[g * OUT + o] = acc;
}

extern "C" void kernel_launch(void* const* d_in, const int* in_sizes, int n_in,
                              void* d_out, int out_size, void* d_ws, size_t ws_size,
                              hipStream_t stream) {
    const float* x          = (const float*)d_in[0];
    const int*   edge_index = (const int*)d_in[1];
    const int*   batch      = (const int*)d_in[2];
    const float* gf         = (const float*)d_in[3];
    const float* W1         = (const float*)d_in[4];
    const float* b1         = (const float*)d_in[5];
    const float* W2         = (const float*)d_in[6];
    const float* b2         = (const float*)d_in[7];
    const float* Wlin       = (const float*)d_in[8];
    const float* blin       = (const float*)d_in[9];
    float* out = (float*)d_out;

    const int N = in_sizes[0] / H;
    const int E = in_sizes[1] / 2;
    const int* src = edge_index;
    const int* dst = edge_index + E;
    const int NBUK = (N + (1 << BSHIFT) - 1) >> BSHIFT;  // 98 for N=100k (<=MAXBUK)

    // workspace layout
    float* ws = (float*)d_ws;
    float* dinv   = ws;                         // N
    uint32* bufA  = (uint32*)(dinv + N);        // N*32 uints (bf16 packed), 16B-aligned
    uint32* bufB  = bufA + (size_t)N * 32;      // N*32 uints
    float* pooled = (float*)(bufB + (size_t)N * 32);  // G*H
    int*   rowptr = (int*)(pooled + G * H);     // N+1
    int*   bcnt   = rowptr + (N + 1);           // MAXBUK
    int*   bbase  = bcnt + MAXBUK;              // MAXBUK+1
    int*   bcur   = bbase + (MAXBUK + 1);       // MAXBUK
    int*   done   = bcur + MAXBUK;              // 1
    size_t off = (size_t)(done + 1 - (int*)d_ws);
    off = (off + 3) & ~(size_t)3;               // 16B align
    uint32* Wb   = (uint32*)d_ws + off;         // 2 * 2048 uints
    int*   csrs  = (int*)(Wb + 2 * 2048);       // E ints
    uint32* inter = (uint32*)(csrs + E);        // E uints (packed ln<<17|src)

    const int T = 256;

    // setup + CSR build (bscan fused into bhist's last block)
    k_setup<<<3, T, 0, stream>>>(W1, W2, Wb, pooled, bcnt, done);
    k_bhist<<<256, T, 0, stream>>>(dst, bcnt, bbase, bcur, done, E, NBUK);
    k_bscatter<<<128, T, 0, stream>>>(src, dst, bcur, inter, E);
    k_build<<<NBUK, T, 0, stream>>>(inter, bbase, rowptr, dinv, csrs, N, NBUK);

    const int NBG = (N + 127) / 128;

    // layer 1
    k_gemm_mfma<0><<<NBG, T, 0, stream>>>(x, Wb, dinv, bufA, N);
    k_aggregate<0><<<(N + 7) / 8, T, 0, stream>>>(bufA, csrs, rowptr, dinv, b1, batch,
                                                  bufB, pooled, N);

    // layer 2 + fused pool
    k_gemm_mfma<1><<<NBG, T, 0, stream>>>(bufB, Wb + 2048, dinv, bufA, N);
    k_aggregate<1><<<(N + 7) / 8, T, 0, stream>>>(bufA, csrs, rowptr, dinv, b2, batch,
                                                  nullptr, pooled, N);

    // head
    k_final<<<1, 128, 0, stream>>>(pooled, gf, Wlin, blin, out);
}